// Round 1
// baseline (1466.628 us; speedup 1.0000x reference)
//
#include <hip/hip_runtime.h>
#include <stdint.h>

#define DIM   1024
#define HID   2816
#define NEXP  2
#define NTOK  32768
#define RMS_EPS 1e-5f

typedef unsigned short u16;
typedef unsigned int   u32;
typedef __bf16 bf16_t;
typedef bf16_t bf16x8 __attribute__((ext_vector_type(8)));
typedef float  f32x4  __attribute__((ext_vector_type(4)));

__device__ __forceinline__ u16 f2bf(float f) {
  u32 u = __float_as_uint(f);
  u += 0x7FFFu + ((u >> 16) & 1u);   // RNE
  return (u16)(u >> 16);
}

__device__ __forceinline__ void gld16(void* lds, const void* g) {
  __builtin_amdgcn_global_load_lds(
      (__attribute__((address_space(1))) void*)g,
      (__attribute__((address_space(3))) void*)lds, 16, 0, 0);
}

// ---------------- mask decoding (layout-robust) ----------------
// 0 = int32 {0,1}; 1 = float32 {0.0,1.0}; 2 = uint8 {0,1}
__device__ __forceinline__ int detect_layout(const u32* mi) {
  const int lane = threadIdx.x & 63;
  bool all01 = true, allf = true;
  for (int j = 0; j < 8; ++j) {
    u32 w = mi[j * 64 + lane];              // first 512 words, always in-bounds
    all01 &= (w <= 1u);
    allf  &= (w == 0u || w == 0x3F800000u);
  }
  unsigned long long b01 = __ballot(all01);
  unsigned long long bfl = __ballot(allf);
  if (b01 == ~0ull) return 0;
  if (bfl == ~0ull) return 1;
  return 2;
}

__device__ __forceinline__ bool mask_at(const void* m, int layout, int e, int n) {
  if (layout == 0) return ((const u32*)m)[e * NTOK + n] != 0u;
  if (layout == 1) return ((const float*)m)[e * NTOK + n] != 0.f;
  return ((const unsigned char*)m)[e * NTOK + n] != 0;
}

__device__ __forceinline__ int label_of(const void* m, int layout, int n) {
  for (int e = 0; e < NEXP; ++e)
    if (mask_at(m, layout, e, n)) return e;  // smallest e wins (matches ref)
  return 0;
}

__global__ void k_count(const void* __restrict__ masks, int* __restrict__ meta) {
  const int layout = detect_layout((const u32*)masks);
  const int n = blockIdx.x * blockDim.x + threadIdx.x;
  if (n < NTOK) atomicAdd(&meta[label_of(masks, layout, n)], 1);
}

__global__ void k_scan(int* __restrict__ meta) {
  if (threadIdx.x == 0) { meta[2] = 0; meta[3] = meta[0]; }
}

__global__ void k_fill(const void* __restrict__ masks, int* __restrict__ meta,
                       int* __restrict__ idx) {
  const int layout = detect_layout((const u32*)masks);
  const int n = blockIdx.x * blockDim.x + threadIdx.x;
  if (n < NTOK) {
    const int e = label_of(masks, layout, n);
    const int pos = atomicAdd(&meta[2 + e], 1);
    idx[pos] = n;
  }
}

// ---------------- f32 -> bf16 conversion (vectorized) ----------------
__global__ void k_cvt(const float* __restrict__ in, u16* __restrict__ out, int n4) {
  const int i = blockIdx.x * blockDim.x + threadIdx.x;
  if (i >= n4) return;
  const float4 v = ((const float4*)in)[i];
  ushort4 o;
  o.x = f2bf(v.x); o.y = f2bf(v.y); o.z = f2bf(v.z); o.w = f2bf(v.w);
  ((ushort4*)out)[i] = o;
}

// ---------------- GEMM1: h = silu(X@W1^T) * (X@W3^T), gathered rows --------
// 128x64 tile (dual B), BK=64, 4 waves (2x2), mfma 16x16x32 bf16.
__global__ __launch_bounds__(256, 2) void k_gemm1(
    const u16* __restrict__ xb, const u16* __restrict__ w1b,
    const u16* __restrict__ w3b, const int* __restrict__ meta,
    const int* __restrict__ idx, u16* __restrict__ h)
{
  const int e    = blockIdx.z;
  const int cnt  = meta[e];
  const int base = e ? meta[0] : 0;
  const int mT   = blockIdx.y;
  const int nT   = blockIdx.x;
  if (mT * 128 >= cnt) return;

  __shared__ __attribute__((aligned(16))) u16 sA[2][128 * 64];
  __shared__ __attribute__((aligned(16))) u16 sB[2][2][64 * 64];

  const int t = threadIdx.x;
  // XOR swizzle (T2): LDS(row, blk) holds global(row, blk ^ (row&7)); involution.
  const int srcblk = (t & 7) ^ ((t >> 3) & 7);

  const u16* aptr[4];
#pragma unroll
  for (int i = 0; i < 4; ++i) {
    const int drow = i * 32 + (t >> 3);
    int rg = mT * 128 + drow;
    rg = rg < cnt ? rg : cnt - 1;
    const int grow = idx[base + rg];
    aptr[i] = xb + (size_t)grow * DIM + srcblk * 8;
  }
  const u16 *b1p[2], *b3p[2];
#pragma unroll
  for (int i = 0; i < 2; ++i) {
    const int drow = i * 32 + (t >> 3);
    const size_t off = ((size_t)e * HID + (size_t)nT * 64 + drow) * DIM + srcblk * 8;
    b1p[i] = w1b + off;
    b3p[i] = w3b + off;
  }

  const int w = t >> 6, l = t & 63;
  const int wr = w >> 1, wc = w & 1;
  const int l15 = l & 15, lk = l >> 4, l7 = l & 7;

  f32x4 acc1[4][2] = {};
  f32x4 acc3[4][2] = {};

  auto stage = [&](int buf, int k0) {
#pragma unroll
    for (int i = 0; i < 4; ++i)
      gld16((char*)(&sA[buf][0]) + i * 4096 + t * 16, aptr[i] + k0);
#pragma unroll
    for (int i = 0; i < 2; ++i) {
      gld16((char*)(&sB[buf][0][0]) + i * 4096 + t * 16, b1p[i] + k0);
      gld16((char*)(&sB[buf][1][0]) + i * 4096 + t * 16, b3p[i] + k0);
    }
  };

  stage(0, 0);
  __syncthreads();
  int cur = 0;
#pragma unroll 2
  for (int kt = 0; kt < 16; ++kt) {
    if (kt + 1 < 16) stage(cur ^ 1, (kt + 1) * 64);
    bf16x8 af[2][4], b1f[2][2], b3f[2][2];
#pragma unroll
    for (int kk = 0; kk < 2; ++kk) {
      const int blk = ((kk * 4 + lk) ^ l7) * 8;
#pragma unroll
      for (int mi = 0; mi < 4; ++mi)
        af[kk][mi] = *(const bf16x8*)&sA[cur][(wr * 64 + mi * 16 + l15) * 64 + blk];
#pragma unroll
      for (int ni = 0; ni < 2; ++ni) {
        b1f[kk][ni] = *(const bf16x8*)&sB[cur][0][(wc * 32 + ni * 16 + l15) * 64 + blk];
        b3f[kk][ni] = *(const bf16x8*)&sB[cur][1][(wc * 32 + ni * 16 + l15) * 64 + blk];
      }
    }
#pragma unroll
    for (int kk = 0; kk < 2; ++kk)
#pragma unroll
      for (int mi = 0; mi < 4; ++mi)
#pragma unroll
        for (int ni = 0; ni < 2; ++ni) {
          acc1[mi][ni] = __builtin_amdgcn_mfma_f32_16x16x32_bf16(
              af[kk][mi], b1f[kk][ni], acc1[mi][ni], 0, 0, 0);
          acc3[mi][ni] = __builtin_amdgcn_mfma_f32_16x16x32_bf16(
              af[kk][mi], b3f[kk][ni], acc3[mi][ni], 0, 0, 0);
        }
    __syncthreads();
    cur ^= 1;
  }

  // epilogue: h = silu(acc1) * acc3, bf16
#pragma unroll
  for (int mi = 0; mi < 4; ++mi)
#pragma unroll
    for (int r = 0; r < 4; ++r) {
      const int rowl = wr * 64 + mi * 16 + lk * 4 + r;
      const int rg = mT * 128 + rowl;
      if (rg < cnt) {
        u16* hrow = h + (size_t)(base + rg) * HID + (size_t)nT * 64 + wc * 32 + l15;
#pragma unroll
        for (int ni = 0; ni < 2; ++ni) {
          const float a = acc1[mi][ni][r];
          const float b = acc3[mi][ni][r];
          const float s = a / (1.f + __expf(-a));
          hrow[ni * 16] = f2bf(s * b);
        }
      }
    }
}

// ---------------- GEMM2: O = H @ W2^T, scatter f32 rows into d_out ----------
// 128x128 tile, BK=64, 4 waves (2x2).
__global__ __launch_bounds__(256, 2) void k_gemm2(
    const u16* __restrict__ hbuf, const u16* __restrict__ w2b,
    const int* __restrict__ meta, const int* __restrict__ idx,
    float* __restrict__ out)
{
  const int e    = blockIdx.z;
  const int cnt  = meta[e];
  const int base = e ? meta[0] : 0;
  const int mT   = blockIdx.y;
  const int nT   = blockIdx.x;
  if (mT * 128 >= cnt) return;

  __shared__ __attribute__((aligned(16))) u16 sA[2][128 * 64];
  __shared__ __attribute__((aligned(16))) u16 sB[2][128 * 64];

  const int t = threadIdx.x;
  const int srcblk = (t & 7) ^ ((t >> 3) & 7);

  const u16 *aptr[4], *bptr[4];
#pragma unroll
  for (int i = 0; i < 4; ++i) {
    const int drow = i * 32 + (t >> 3);
    int rg = mT * 128 + drow;
    rg = rg < cnt ? rg : cnt - 1;
    aptr[i] = hbuf + (size_t)(base + rg) * HID + srcblk * 8;
    bptr[i] = w2b + ((size_t)e * DIM + (size_t)nT * 128 + drow) * HID + srcblk * 8;
  }

  const int w = t >> 6, l = t & 63;
  const int wr = w >> 1, wc = w & 1;
  const int l15 = l & 15, lk = l >> 4, l7 = l & 7;

  f32x4 acc[4][4] = {};

  auto stage = [&](int buf, int k0) {
#pragma unroll
    for (int i = 0; i < 4; ++i) {
      gld16((char*)(&sA[buf][0]) + i * 4096 + t * 16, aptr[i] + k0);
      gld16((char*)(&sB[buf][0]) + i * 4096 + t * 16, bptr[i] + k0);
    }
  };

  stage(0, 0);
  __syncthreads();
  int cur = 0;
#pragma unroll 2
  for (int kt = 0; kt < 44; ++kt) {
    if (kt + 1 < 44) stage(cur ^ 1, (kt + 1) * 64);
    bf16x8 af[2][4], bf[2][4];
#pragma unroll
    for (int kk = 0; kk < 2; ++kk) {
      const int blk = ((kk * 4 + lk) ^ l7) * 8;
#pragma unroll
      for (int mi = 0; mi < 4; ++mi)
        af[kk][mi] = *(const bf16x8*)&sA[cur][(wr * 64 + mi * 16 + l15) * 64 + blk];
#pragma unroll
      for (int ni = 0; ni < 4; ++ni)
        bf[kk][ni] = *(const bf16x8*)&sB[cur][(wc * 64 + ni * 16 + l15) * 64 + blk];
    }
#pragma unroll
    for (int kk = 0; kk < 2; ++kk)
#pragma unroll
      for (int mi = 0; mi < 4; ++mi)
#pragma unroll
        for (int ni = 0; ni < 4; ++ni)
          acc[mi][ni] = __builtin_amdgcn_mfma_f32_16x16x32_bf16(
              af[kk][mi], bf[kk][ni], acc[mi][ni], 0, 0, 0);
    __syncthreads();
    cur ^= 1;
  }

#pragma unroll
  for (int mi = 0; mi < 4; ++mi)
#pragma unroll
    for (int r = 0; r < 4; ++r) {
      const int rowl = wr * 64 + mi * 16 + lk * 4 + r;
      const int rg = mT * 128 + rowl;
      if (rg < cnt) {
        const int tok = idx[base + rg];
        float* orow = out + (size_t)tok * DIM + (size_t)nT * 128 + wc * 64 + l15;
#pragma unroll
        for (int ni = 0; ni < 4; ++ni)
          orow[ni * 16] = acc[mi][ni][r];
      }
    }
}

// ---------------- RMSNorm in-place on d_out (per token row) ----------------
__global__ __launch_bounds__(256) void k_rms(
    float* __restrict__ out, const float* __restrict__ nw,
    const int* __restrict__ meta, const int* __restrict__ idx)
{
  const int r = blockIdx.x;            // gathered row 0..N-1
  const int e = (r >= meta[0]) ? 1 : 0;
  const int tok = idx[r];
  float* row = out + (size_t)tok * DIM;
  const int t = threadIdx.x;

  float4 v = ((const float4*)row)[t];
  float ss = v.x * v.x + v.y * v.y + v.z * v.z + v.w * v.w;
#pragma unroll
  for (int off = 32; off; off >>= 1) ss += __shfl_xor(ss, off, 64);

  __shared__ float red[4];
  const int l = t & 63, wv = t >> 6;
  if (l == 0) red[wv] = ss;
  __syncthreads();
  const float tot = red[0] + red[1] + red[2] + red[3];
  const float scale = rsqrtf(tot * (1.0f / DIM) + RMS_EPS);

  const float4 g = ((const float4*)(nw + (size_t)e * DIM))[t];
  v.x *= scale * g.x; v.y *= scale * g.y;
  v.z *= scale * g.z; v.w *= scale * g.w;
  ((float4*)row)[t] = v;
}

// ---------------- launch ----------------
extern "C" void kernel_launch(void* const* d_in, const int* in_sizes, int n_in,
                              void* d_out, int out_size, void* d_ws, size_t ws_size,
                              hipStream_t stream)
{
  const float* x     = (const float*)d_in[0];
  const void*  masks = d_in[1];
  const float* w1    = (const float*)d_in[2];
  const float* w3    = (const float*)d_in[3];
  const float* w2    = (const float*)d_in[4];
  const float* nw    = (const float*)d_in[5];
  float* out = (float*)d_out;

  char* ws = (char*)d_ws;
  constexpr size_t OFF_IDX = 256;
  constexpr size_t OFF_XB  = OFF_IDX + (size_t)NTOK * 4;
  constexpr size_t OFF_W1B = OFF_XB + (size_t)NTOK * DIM * 2;
  constexpr size_t SZ_W    = (size_t)NEXP * HID * DIM * 2;
  constexpr size_t OFF_W3B = OFF_W1B + SZ_W;
  constexpr size_t OFF_W2B = OFF_W3B + SZ_W;
  constexpr size_t OFF_H   = OFF_W2B + SZ_W;

  int* meta = (int*)ws;
  int* idx  = (int*)(ws + OFF_IDX);
  u16* xb   = (u16*)(ws + OFF_XB);
  u16* w1b  = (u16*)(ws + OFF_W1B);
  u16* w3b  = (u16*)(ws + OFF_W3B);
  u16* w2b  = (u16*)(ws + OFF_W2B);
  u16* h    = (u16*)(ws + OFF_H);

  hipMemsetAsync(meta, 0, 16, stream);
  k_count<<<NTOK / 256, 256, 0, stream>>>(masks, meta);
  k_scan<<<1, 64, 0, stream>>>(meta);
  k_fill<<<NTOK / 256, 256, 0, stream>>>(masks, meta, idx);

  const int wn4 = NEXP * HID * DIM / 4;
  k_cvt<<<(wn4 + 255) / 256, 256, 0, stream>>>(w1, w1b, wn4);
  k_cvt<<<(wn4 + 255) / 256, 256, 0, stream>>>(w3, w3b, wn4);
  k_cvt<<<(wn4 + 255) / 256, 256, 0, stream>>>(w2, w2b, wn4);
  const int xn4 = NTOK * DIM / 4;
  k_cvt<<<(xn4 + 255) / 256, 256, 0, stream>>>(x, xb, xn4);

  k_gemm1<<<dim3(HID / 64, NTOK / 128, NEXP), 256, 0, stream>>>(
      xb, w1b, w3b, meta, idx, h);
  k_gemm2<<<dim3(DIM / 128, NTOK / 128, NEXP), 256, 0, stream>>>(
      h, w2b, meta, idx, out);
  k_rms<<<NTOK, 256, 0, stream>>>(out, nw, meta, idx);
}

// Round 2
// 1339.877 us; speedup vs baseline: 1.0946x; 1.0946x over previous
//
#include <hip/hip_runtime.h>
#include <stdint.h>

#define DIM   1024
#define HID   2816
#define NEXP  2
#define NTOK  32768
#define RMS_EPS 1e-5f
#define NK1 (DIM / 64)   // 16 K-tiles for GEMM1
#define NK2 (HID / 64)   // 44 K-tiles for GEMM2

typedef unsigned short u16;
typedef unsigned int   u32;
typedef __bf16 bf16_t;
typedef bf16_t bf16x8 __attribute__((ext_vector_type(8)));
typedef float  f32x4  __attribute__((ext_vector_type(4)));

#define BAR() asm volatile("s_barrier" ::: "memory")
#define MFMA_(a,b,c) __builtin_amdgcn_mfma_f32_16x16x32_bf16(a, b, c, 0, 0, 0)

__device__ __forceinline__ u16 f2bf(float f) {
  u32 u = __float_as_uint(f);
  u += 0x7FFFu + ((u >> 16) & 1u);   // RNE
  return (u16)(u >> 16);
}

__device__ __forceinline__ void gld16(void* lds, const void* g) {
  __builtin_amdgcn_global_load_lds(
      (__attribute__((address_space(1))) void*)g,
      (__attribute__((address_space(3))) void*)lds, 16, 0, 0);
}

// ---------------- mask decoding (layout-robust) ----------------
__device__ __forceinline__ int detect_layout(const u32* mi) {
  const int lane = threadIdx.x & 63;
  bool all01 = true, allf = true;
  for (int j = 0; j < 8; ++j) {
    u32 w = mi[j * 64 + lane];
    all01 &= (w <= 1u);
    allf  &= (w == 0u || w == 0x3F800000u);
  }
  unsigned long long b01 = __ballot(all01);
  unsigned long long bfl = __ballot(allf);
  if (b01 == ~0ull) return 0;
  if (bfl == ~0ull) return 1;
  return 2;
}

__device__ __forceinline__ bool mask_at(const void* m, int layout, int e, int n) {
  if (layout == 0) return ((const u32*)m)[e * NTOK + n] != 0u;
  if (layout == 1) return ((const float*)m)[e * NTOK + n] != 0.f;
  return ((const unsigned char*)m)[e * NTOK + n] != 0;
}

__device__ __forceinline__ int label_of(const void* m, int layout, int n) {
  for (int e = 0; e < NEXP; ++e)
    if (mask_at(m, layout, e, n)) return e;
  return 0;
}

__global__ void k_count(const void* __restrict__ masks, int* __restrict__ meta) {
  const int layout = detect_layout((const u32*)masks);
  const int n = blockIdx.x * blockDim.x + threadIdx.x;
  if (n < NTOK) atomicAdd(&meta[label_of(masks, layout, n)], 1);
}

__global__ void k_scan(int* __restrict__ meta) {
  if (threadIdx.x == 0) { meta[2] = 0; meta[3] = meta[0]; }
}

__global__ void k_fill(const void* __restrict__ masks, int* __restrict__ meta,
                       int* __restrict__ idx) {
  const int layout = detect_layout((const u32*)masks);
  const int n = blockIdx.x * blockDim.x + threadIdx.x;
  if (n < NTOK) {
    const int e = label_of(masks, layout, n);
    const int pos = atomicAdd(&meta[2 + e], 1);
    idx[pos] = n;
  }
}

// ---------------- f32 -> bf16 conversion ----------------
__global__ void k_cvt(const float* __restrict__ in, u16* __restrict__ out, int n4) {
  const int i = blockIdx.x * blockDim.x + threadIdx.x;
  if (i >= n4) return;
  const float4 v = ((const float4*)in)[i];
  ushort4 o;
  o.x = f2bf(v.x); o.y = f2bf(v.y); o.z = f2bf(v.z); o.w = f2bf(v.w);
  ((ushort4*)out)[i] = o;
}

// ============================================================================
// GEMM1: h = silu(X@W1^T) * (X@W3^T), gathered rows.
// 8-phase counted-vmcnt schedule. BM=256, BN=128 (dual B), BK=64,
// 8 waves (2M x 4N), 128 KiB LDS (2 dbuf).
// Quadrant interleave: wave output rows = mq*128 + wr*64 + mi*16 (+frag),
// cols = nq*64 + wc*16 (+frag). Phase q=(mq,nq) touches A-half mq, B-half nq.
// ============================================================================

// staging: thread t covers chunk c (16B) -> row c>>3, blk c&7, pre-swizzled src.
#define G1_STAGE_A(BUF, HH, KT) {                                     \
    char* _d = (char*)&sA[BUF][(HH) * 8192] + t * 16;                 \
    gld16(_d,        ((HH) ? aptr2 : aptr0) + (size_t)(KT) * 64);     \
    gld16(_d + 8192, ((HH) ? aptr3 : aptr1) + (size_t)(KT) * 64); }

#define G1_STAGE_B(BUF, HH, KT) {                                     \
    gld16((char*)&sB1[BUF][(HH) * 4096] + t * 16,                     \
          ((HH) ? b1p1 : b1p0) + (size_t)(KT) * 64);                  \
    gld16((char*)&sB3[BUF][(HH) * 4096] + t * 16,                     \
          ((HH) ? b3p1 : b3p0) + (size_t)(KT) * 64); }

#define G1_PH(MQ, NQ, ...) {                                                   \
    if ((NQ) == 0) {                                                           \
      _Pragma("unroll") for (int mi = 0; mi < 4; ++mi) {                       \
        af0[mi] = *(const bf16x8*)&sAc[aBase + (MQ)*8192 + mi*1024 + kb0];     \
        af1[mi] = *(const bf16x8*)&sAc[aBase + (MQ)*8192 + mi*1024 + kb1];     \
      }                                                                        \
    }                                                                          \
    b1f0 = *(const bf16x8*)&sB1c[bBase + (NQ)*4096 + kb0];                     \
    b1f1 = *(const bf16x8*)&sB1c[bBase + (NQ)*4096 + kb1];                     \
    b3f0 = *(const bf16x8*)&sB3c[bBase + (NQ)*4096 + kb0];                     \
    b3f1 = *(const bf16x8*)&sB3c[bBase + (NQ)*4096 + kb1];                     \
    __VA_ARGS__                                                                \
    BAR();                                                                     \
    __builtin_amdgcn_s_setprio(1);                                             \
    _Pragma("unroll") for (int mi = 0; mi < 4; ++mi) {                         \
      acc1[MQ][NQ][mi] = MFMA_(af0[mi], b1f0, acc1[MQ][NQ][mi]);               \
      acc3[MQ][NQ][mi] = MFMA_(af0[mi], b3f0, acc3[MQ][NQ][mi]);               \
      acc1[MQ][NQ][mi] = MFMA_(af1[mi], b1f1, acc1[MQ][NQ][mi]);               \
      acc3[MQ][NQ][mi] = MFMA_(af1[mi], b3f1, acc3[MQ][NQ][mi]);               \
    }                                                                          \
    __builtin_amdgcn_s_setprio(0);                                             \
  }

__global__ __launch_bounds__(512, 2) void k_gemm1(
    const u16* __restrict__ xb, const u16* __restrict__ w1b,
    const u16* __restrict__ w3b, const int* __restrict__ meta,
    const int* __restrict__ idx, u16* __restrict__ h)
{
  const int e    = blockIdx.z;
  const int cnt  = meta[e];
  const int base = e ? meta[0] : 0;
  const int mT   = blockIdx.y;
  const int nT   = blockIdx.x;
  if (mT * 256 >= cnt) return;

  __shared__ __attribute__((aligned(16))) u16 sA [2][256 * 64];
  __shared__ __attribute__((aligned(16))) u16 sB1[2][128 * 64];
  __shared__ __attribute__((aligned(16))) u16 sB3[2][128 * 64];

  const int t = threadIdx.x;
  const int srcoff = ((t & 7) ^ ((t >> 3) & 7)) * 8;   // pre-swizzled src (u16)
  const int r0 = t >> 3;

  const u16 *aptr0, *aptr1, *aptr2, *aptr3;
  {
    int rg;
    rg = mT*256 +   0 + r0; rg = rg < cnt ? rg : cnt-1; aptr0 = xb + (size_t)idx[base+rg]*DIM + srcoff;
    rg = mT*256 +  64 + r0; rg = rg < cnt ? rg : cnt-1; aptr1 = xb + (size_t)idx[base+rg]*DIM + srcoff;
    rg = mT*256 + 128 + r0; rg = rg < cnt ? rg : cnt-1; aptr2 = xb + (size_t)idx[base+rg]*DIM + srcoff;
    rg = mT*256 + 192 + r0; rg = rg < cnt ? rg : cnt-1; aptr3 = xb + (size_t)idx[base+rg]*DIM + srcoff;
  }
  const u16 *b1p0, *b1p1, *b3p0, *b3p1;
  {
    size_t o0 = ((size_t)e * HID + (size_t)nT * 128 +      r0) * DIM + srcoff;
    size_t o1 = ((size_t)e * HID + (size_t)nT * 128 + 64 + r0) * DIM + srcoff;
    b1p0 = w1b + o0; b1p1 = w1b + o1;
    b3p0 = w3b + o0; b3p1 = w3b + o1;
  }

  const int wid = t >> 6, l = t & 63;
  const int wr = wid >> 2, wc = wid & 3;
  const int l15 = l & 15, lk = l >> 4, l7 = l & 7;
  const int kb0 = ((0 + lk) ^ l7) * 8;
  const int kb1 = ((4 + lk) ^ l7) * 8;
  const int aBase = (wr * 64 + l15) * 64;
  const int bBase = (wc * 16 + l15) * 64;

  f32x4 acc1[2][2][4] = {};
  f32x4 acc3[2][2][4] = {};
  bf16x8 af0[4], af1[4], b1f0, b1f1, b3f0, b3f1;

  // prologue: tile0 full (8 loads) + tile1 {A0,A1,Bh0} (6 loads)
  G1_STAGE_A(0, 0, 0) G1_STAGE_A(0, 1, 0) G1_STAGE_B(0, 0, 0) G1_STAGE_B(0, 1, 0)
  G1_STAGE_A(1, 0, 1) G1_STAGE_A(1, 1, 1) G1_STAGE_B(1, 0, 1)
  asm volatile("s_waitcnt vmcnt(6)" ::: "memory");
  BAR();

#pragma unroll 2
  for (int k = 0; k < NK1; ++k) {
    const u16* sAc  = &sA [k & 1][0];
    const u16* sB1c = &sB1[k & 1][0];
    const u16* sB3c = &sB3[k & 1][0];
    const int nb = (k & 1) ^ 1;
    const bool p1 = (k + 1 < NK1), p2 = (k + 2 < NK1);

    G1_PH(0, 0, if (p1) G1_STAGE_B(nb, 1, k + 1))          // stage B-half1(k+1)
    BAR();
    G1_PH(0, 1, if (p2) G1_STAGE_A(k & 1, 0, k + 2))       // stage A-half0(k+2)
    BAR();
    G1_PH(1, 0, )
    BAR();
    G1_PH(1, 1, if (p2) { G1_STAGE_A(k & 1, 1, k + 2) G1_STAGE_B(k & 1, 0, k + 2) })
    if (p1) {
      if (p2) asm volatile("s_waitcnt vmcnt(6)" ::: "memory");
      else    asm volatile("s_waitcnt vmcnt(0)" ::: "memory");
    }
    BAR();
  }

  // epilogue: h = silu(acc1) * acc3
#pragma unroll
  for (int mq = 0; mq < 2; ++mq)
#pragma unroll
    for (int mi = 0; mi < 4; ++mi)
#pragma unroll
      for (int r = 0; r < 4; ++r) {
        const int lrow = mq * 128 + wr * 64 + mi * 16 + lk * 4 + r;
        const int rg = mT * 256 + lrow;
        if (rg < cnt) {
          u16* hrow = h + (size_t)(base + rg) * HID + nT * 128 + wc * 16 + l15;
#pragma unroll
          for (int nq = 0; nq < 2; ++nq) {
            const float a = acc1[mq][nq][mi][r];
            const float b = acc3[mq][nq][mi][r];
            hrow[nq * 64] = f2bf((a / (1.f + __expf(-a))) * b);
          }
        }
      }
}

// ============================================================================
// GEMM2: O = H @ W2^T, scatter f32 rows. BM=256, BN=256, BK=64, 8 waves.
// ============================================================================

#define G2_STAGE_A(BUF, HH, KT) {                                     \
    char* _d = (char*)&sA[BUF][(HH) * 8192] + t * 16;                 \
    gld16(_d,        ((HH) ? aptr2 : aptr0) + (size_t)(KT) * 64);     \
    gld16(_d + 8192, ((HH) ? aptr3 : aptr1) + (size_t)(KT) * 64); }

#define G2_STAGE_B(BUF, HH, KT) {                                     \
    char* _d = (char*)&sB[BUF][(HH) * 8192] + t * 16;                 \
    gld16(_d,        ((HH) ? bptr2 : bptr0) + (size_t)(KT) * 64);     \
    gld16(_d + 8192, ((HH) ? bptr3 : bptr1) + (size_t)(KT) * 64); }

#define G2_PH(MQ, NQ, ...) {                                                   \
    if ((NQ) == 0) {                                                           \
      _Pragma("unroll") for (int mi = 0; mi < 4; ++mi) {                       \
        af0[mi] = *(const bf16x8*)&sAc[aBase + (MQ)*8192 + mi*1024 + kb0];     \
        af1[mi] = *(const bf16x8*)&sAc[aBase + (MQ)*8192 + mi*1024 + kb1];     \
      }                                                                        \
    }                                                                          \
    _Pragma("unroll") for (int ni = 0; ni < 2; ++ni) {                         \
      bf0[ni] = *(const bf16x8*)&sBc[bBase + (NQ)*8192 + ni*1024 + kb0];       \
      bf1[ni] = *(const bf16x8*)&sBc[bBase + (NQ)*8192 + ni*1024 + kb1];       \
    }                                                                          \
    __VA_ARGS__                                                                \
    BAR();                                                                     \
    __builtin_amdgcn_s_setprio(1);                                             \
    _Pragma("unroll") for (int mi = 0; mi < 4; ++mi)                           \
      _Pragma("unroll") for (int ni = 0; ni < 2; ++ni) {                       \
        acc[MQ][NQ][mi][ni] = MFMA_(af0[mi], bf0[ni], acc[MQ][NQ][mi][ni]);    \
        acc[MQ][NQ][mi][ni] = MFMA_(af1[mi], bf1[ni], acc[MQ][NQ][mi][ni]);    \
      }                                                                        \
    __builtin_amdgcn_s_setprio(0);                                             \
  }

__global__ __launch_bounds__(512, 2) void k_gemm2(
    const u16* __restrict__ hbuf, const u16* __restrict__ w2b,
    const int* __restrict__ meta, const int* __restrict__ idx,
    float* __restrict__ out)
{
  const int e    = blockIdx.z;
  const int cnt  = meta[e];
  const int base = e ? meta[0] : 0;
  const int mT   = blockIdx.y;
  const int nT   = blockIdx.x;
  if (mT * 256 >= cnt) return;

  __shared__ __attribute__((aligned(16))) u16 sA[2][256 * 64];
  __shared__ __attribute__((aligned(16))) u16 sB[2][256 * 64];

  const int t = threadIdx.x;
  const int srcoff = ((t & 7) ^ ((t >> 3) & 7)) * 8;
  const int r0 = t >> 3;

  const u16 *aptr0, *aptr1, *aptr2, *aptr3;
  {
    int rg;
    rg = mT*256 +   0 + r0; rg = rg < cnt ? rg : cnt-1; aptr0 = hbuf + (size_t)(base+rg)*HID + srcoff;
    rg = mT*256 +  64 + r0; rg = rg < cnt ? rg : cnt-1; aptr1 = hbuf + (size_t)(base+rg)*HID + srcoff;
    rg = mT*256 + 128 + r0; rg = rg < cnt ? rg : cnt-1; aptr2 = hbuf + (size_t)(base+rg)*HID + srcoff;
    rg = mT*256 + 192 + r0; rg = rg < cnt ? rg : cnt-1; aptr3 = hbuf + (size_t)(base+rg)*HID + srcoff;
  }
  const u16 *bptr0, *bptr1, *bptr2, *bptr3;
  {
    const size_t wb = (size_t)e * DIM + (size_t)nT * 256;
    bptr0 = w2b + (wb +       r0) * HID + srcoff;
    bptr1 = w2b + (wb +  64 + r0) * HID + srcoff;
    bptr2 = w2b + (wb + 128 + r0) * HID + srcoff;
    bptr3 = w2b + (wb + 192 + r0) * HID + srcoff;
  }

  const int wid = t >> 6, l = t & 63;
  const int wr = wid >> 2, wc = wid & 3;
  const int l15 = l & 15, lk = l >> 4, l7 = l & 7;
  const int kb0 = ((0 + lk) ^ l7) * 8;
  const int kb1 = ((4 + lk) ^ l7) * 8;
  const int aBase = (wr * 64 + l15) * 64;
  const int bBase = (wc * 32 + l15) * 64;

  f32x4 acc[2][2][4][2] = {};
  bf16x8 af0[4], af1[4], bf0[2], bf1[2];

  // prologue
  G2_STAGE_A(0, 0, 0) G2_STAGE_A(0, 1, 0) G2_STAGE_B(0, 0, 0) G2_STAGE_B(0, 1, 0)
  G2_STAGE_A(1, 0, 1) G2_STAGE_A(1, 1, 1) G2_STAGE_B(1, 0, 1)
  asm volatile("s_waitcnt vmcnt(6)" ::: "memory");
  BAR();

#pragma unroll 2
  for (int k = 0; k < NK2; ++k) {
    const u16* sAc = &sA[k & 1][0];
    const u16* sBc = &sB[k & 1][0];
    const int nb = (k & 1) ^ 1;
    const bool p1 = (k + 1 < NK2), p2 = (k + 2 < NK2);

    G2_PH(0, 0, if (p1) G2_STAGE_B(nb, 1, k + 1))
    BAR();
    G2_PH(0, 1, if (p2) G2_STAGE_A(k & 1, 0, k + 2))
    BAR();
    G2_PH(1, 0, )
    BAR();
    G2_PH(1, 1, if (p2) { G2_STAGE_A(k & 1, 1, k + 2) G2_STAGE_B(k & 1, 0, k + 2) })
    if (p1) {
      if (p2) asm volatile("s_waitcnt vmcnt(6)" ::: "memory");
      else    asm volatile("s_waitcnt vmcnt(0)" ::: "memory");
    }
    BAR();
  }

#pragma unroll
  for (int mq = 0; mq < 2; ++mq)
#pragma unroll
    for (int mi = 0; mi < 4; ++mi)
#pragma unroll
      for (int r = 0; r < 4; ++r) {
        const int lrow = mq * 128 + wr * 64 + mi * 16 + lk * 4 + r;
        const int rg = mT * 256 + lrow;
        if (rg < cnt) {
          const int tok = idx[base + rg];
          float* orow = out + (size_t)tok * DIM + nT * 256 + wc * 32 + l15;
#pragma unroll
          for (int nq = 0; nq < 2; ++nq)
#pragma unroll
            for (int ni = 0; ni < 2; ++ni)
              orow[nq * 128 + ni * 16] = acc[mq][nq][mi][ni][r];
        }
      }
}

// ---------------- RMSNorm in-place on d_out ----------------
__global__ __launch_bounds__(256) void k_rms(
    float* __restrict__ out, const float* __restrict__ nw,
    const int* __restrict__ meta, const int* __restrict__ idx)
{
  const int r = blockIdx.x;
  const int e = (r >= meta[0]) ? 1 : 0;
  const int tok = idx[r];
  float* row = out + (size_t)tok * DIM;
  const int t = threadIdx.x;

  float4 v = ((const float4*)row)[t];
  float ss = v.x * v.x + v.y * v.y + v.z * v.z + v.w * v.w;
#pragma unroll
  for (int off = 32; off; off >>= 1) ss += __shfl_xor(ss, off, 64);

  __shared__ float red[4];
  const int l = t & 63, wv = t >> 6;
  if (l == 0) red[wv] = ss;
  __syncthreads();
  const float tot = red[0] + red[1] + red[2] + red[3];
  const float scale = rsqrtf(tot * (1.0f / DIM) + RMS_EPS);

  const float4 g = ((const float4*)(nw + (size_t)e * DIM))[t];
  v.x *= scale * g.x; v.y *= scale * g.y;
  v.z *= scale * g.z; v.w *= scale * g.w;
  ((float4*)row)[t] = v;
}

// ---------------- launch ----------------
extern "C" void kernel_launch(void* const* d_in, const int* in_sizes, int n_in,
                              void* d_out, int out_size, void* d_ws, size_t ws_size,
                              hipStream_t stream)
{
  const float* x     = (const float*)d_in[0];
  const void*  masks = d_in[1];
  const float* w1    = (const float*)d_in[2];
  const float* w3    = (const float*)d_in[3];
  const float* w2    = (const float*)d_in[4];
  const float* nw    = (const float*)d_in[5];
  float* out = (float*)d_out;

  char* ws = (char*)d_ws;
  constexpr size_t OFF_IDX = 256;
  constexpr size_t OFF_XB  = OFF_IDX + (size_t)NTOK * 4;
  constexpr size_t OFF_W1B = OFF_XB + (size_t)NTOK * DIM * 2;
  constexpr size_t SZ_W    = (size_t)NEXP * HID * DIM * 2;
  constexpr size_t OFF_W3B = OFF_W1B + SZ_W;
  constexpr size_t OFF_W2B = OFF_W3B + SZ_W;
  constexpr size_t OFF_H   = OFF_W2B + SZ_W;

  int* meta = (int*)ws;
  int* idx  = (int*)(ws + OFF_IDX);
  u16* xb   = (u16*)(ws + OFF_XB);
  u16* w1b  = (u16*)(ws + OFF_W1B);
  u16* w3b  = (u16*)(ws + OFF_W3B);
  u16* w2b  = (u16*)(ws + OFF_W2B);
  u16* h    = (u16*)(ws + OFF_H);

  hipMemsetAsync(meta, 0, 16, stream);
  k_count<<<NTOK / 256, 256, 0, stream>>>(masks, meta);
  k_scan<<<1, 64, 0, stream>>>(meta);
  k_fill<<<NTOK / 256, 256, 0, stream>>>(masks, meta, idx);

  const int wn4 = NEXP * HID * DIM / 4;
  k_cvt<<<(wn4 + 255) / 256, 256, 0, stream>>>(w1, w1b, wn4);
  k_cvt<<<(wn4 + 255) / 256, 256, 0, stream>>>(w3, w3b, wn4);
  k_cvt<<<(wn4 + 255) / 256, 256, 0, stream>>>(w2, w2b, wn4);
  const int xn4 = NTOK * DIM / 4;
  k_cvt<<<(xn4 + 255) / 256, 256, 0, stream>>>(x, xb, xn4);

  k_gemm1<<<dim3(HID / 128, NTOK / 256, NEXP), 512, 0, stream>>>(
      xb, w1b, w3b, meta, idx, h);
  k_gemm2<<<dim3(DIM / 256, NTOK / 256, NEXP), 512, 0, stream>>>(
      h, w2b, meta, idx, out);
  k_rms<<<NTOK, 256, 0, stream>>>(out, nw, meta, idx);
}